// Round 12
// baseline (66.454 us; speedup 1.0000x reference)
//
#include <hip/hip_runtime.h>
#include <hip/hip_fp16.h>
#include <math.h>

#define NROWS 50000
#define D 128
#define KNB 16

typedef _Float16 f16;
typedef _Float16 f16x8 __attribute__((ext_vector_type(8)));
typedef _Float16 f16x2 __attribute__((ext_vector_type(2)));
typedef float f32x4 __attribute__((ext_vector_type(4)));
typedef float f32x2 __attribute__((ext_vector_type(2)));
typedef unsigned int u32;

// ---- fused gemm: W->LDS(f16,swizzled); per wave 16 rows: fp8n row, then MFMA ->
//      C to LDS (swizzled, conflict-free) -> coalesced 16B global stores ----
__global__ __launch_bounds__(512) void gemm_kernel(const float* __restrict__ fp,
                                                   const float* __restrict__ W,
                                                   const float* __restrict__ b,
                                                   unsigned char* __restrict__ fp8n,
                                                   f16* __restrict__ Yh,
                                                   f16* __restrict__ baseh,
                                                   float* __restrict__ basef,
                                                   int use16) {
    __shared__ f16 wlds[256 * 128];   // Wcat[col][k], chunk-swizzled: chunk ^= (col&15)
    __shared__ f16 clds[8 * 4096];    // per-wave 16x256 C tile (chunk ^= row>>2)
    int tid = threadIdx.x;
    int wid = tid >> 6, lane = tid & 63;
    int r = lane & 15, kg = lane >> 4;
    int row0 = blockIdx.x * 128 + wid * 16;
    bool valid = row0 < NROWS;

    // --- hoist fp row loads + bias loads above staging (latency overlap) ---
    f32x4 v[8];
    float bias8[8];
    if (valid) {
        const float* src = fp + (size_t)(row0 + r) * D + kg * 8;
        #pragma unroll
        for (int kc = 0; kc < 4; ++kc) {
            v[2 * kc]     = *(const f32x4*)(src + kc * 32);
            v[2 * kc + 1] = *(const f32x4*)(src + kc * 32 + 4);
        }
        #pragma unroll
        for (int q = 0; q < 8; ++q) bias8[q] = b[q * 16 + r];
    }

    // stage W (128x256 f32) -> LDS as f16 concat layout, coalesced 32B reads per thread
    #pragma unroll
    for (int it = 0; it < 8; ++it) {
        int g = tid + it * 512;          // 8-float group, 4096 total
        int i = g * 8;                   // flat index into W
        int c_w = i >> 8;                // W row (0..127)
        int kk = i & 255;                // W col (0..255)
        int destrow = (kk < 128) ? c_w : c_w + 128;
        int k = kk & 127;
        int chunk = (k >> 3) ^ (destrow & 15);
        f32x4 v0 = *(const f32x4*)(W + i);
        f32x4 v1 = *(const f32x4*)(W + i + 4);
        f16x8 h;
        #pragma unroll
        for (int e = 0; e < 4; ++e) { h[e] = (f16)v0[e]; h[4 + e] = (f16)v1[e]; }
        *(f16x8*)(wlds + destrow * 128 + chunk * 8) = h;
    }
    __syncthreads();
    if (!valid) return;

    float ssq = 0.f;
    #pragma unroll
    for (int q = 0; q < 8; ++q) {
        #pragma unroll
        for (int e = 0; e < 4; ++e) ssq = fmaf(v[q][e], v[q][e], ssq);
    }
    ssq += __shfl_xor(ssq, 16, 64);
    ssq += __shfl_xor(ssq, 32, 64);      // all lanes: full row ssq
    float rn = rsqrtf(ssq);

    // A-frags (f16, unnormalized) + fp8 e4m3 normalized row for the cosine table
    f16x8 a[4];
    #pragma unroll
    for (int kc = 0; kc < 4; ++kc) {
        f16x8 h;
        float nx[8];
        #pragma unroll
        for (int e = 0; e < 4; ++e) {
            float x0 = v[2 * kc][e], x1 = v[2 * kc + 1][e];
            h[e] = (f16)x0;        h[4 + e] = (f16)x1;
            nx[e] = x0 * rn;       nx[4 + e] = x1 * rn;
        }
        a[kc] = h;
        u32 lo = __builtin_amdgcn_cvt_pk_fp8_f32(nx[0], nx[1], 0u, false);
        lo     = __builtin_amdgcn_cvt_pk_fp8_f32(nx[2], nx[3], lo, true);
        u32 hi = __builtin_amdgcn_cvt_pk_fp8_f32(nx[4], nx[5], 0u, false);
        hi     = __builtin_amdgcn_cvt_pk_fp8_f32(nx[6], nx[7], hi, true);
        uint2 st; st.x = lo; st.y = hi;
        *(uint2*)(fp8n + (size_t)(row0 + r) * 128 + kc * 32 + kg * 8) = st;
    }

    // MFMA; C -> clds (per-wave region, chunk-XOR swizzle: conflict-free b16 writes)
    f16* cw = clds + wid * 4096;
    #pragma unroll 4
    for (int ct = 0; ct < 16; ++ct) {
        int col = ct * 16 + r;
        f32x4 acc = {0.f, 0.f, 0.f, 0.f};
        #pragma unroll
        for (int kc = 0; kc < 4; ++kc) {
            int sc = (kc * 4 + kg) ^ r;  // swizzled chunk (matches staging XOR)
            f16x8 bf = *(const f16x8*)(wlds + col * 128 + sc * 8);
            acc = __builtin_amdgcn_mfma_f32_16x16x32_f16(a[kc], bf, acc, 0, 0, 0);
        }
        float add = (ct >= 8) ? bias8[ct - 8] : 0.0f;
        #pragma unroll
        for (int i = 0; i < 4; ++i) {
            int row = kg * 4 + i;        // 0..15
            int cidx = row * 256 + (((col >> 3) ^ (row >> 2)) << 3) + (col & 7);
            cw[cidx] = (f16)(acc[i] + add);
        }
    }

    // coalesced flush: each lane 8 chunks of 16B from its wave's region
    #pragma unroll
    for (int it = 0; it < 8; ++it) {
        int c = lane + it * 64;          // chunk id 0..511
        int row = c >> 5;                // 0..15
        int cc = c & 31;                 // logical 8-f16 chunk within row
        f16x8 val = *(const f16x8*)(cw + row * 256 + ((cc ^ (row >> 2)) << 3));
        int col0 = cc * 8;               // 0..248
        size_t grow = (size_t)(row0 + row) * 128;
        if (col0 < 128) {
            *(f16x8*)(Yh + grow + col0) = val;
        } else if (use16) {
            *(f16x8*)(baseh + grow + (col0 - 128)) = val;
        } else {
            f32x4 lo, hi;
            #pragma unroll
            for (int e = 0; e < 4; ++e) { lo[e] = (float)val[e]; hi[e] = (float)val[4 + e]; }
            *(f32x4*)(basef + grow + (col0 - 128)) = lo;
            *(f32x4*)(basef + grow + (col0 - 124)) = hi;
        }
    }
}

// ---- main: one wave per n; all 16 Y-gathers issued first; fp8 cosine dots ----
__global__ __launch_bounds__(256) void main_kernel(const unsigned char* __restrict__ fp8n,
                                                   const int* __restrict__ idx,
                                                   const f16* __restrict__ Yh,
                                                   const f16* __restrict__ baseh,
                                                   float* __restrict__ out,
                                                   int use16) {
    int wid = threadIdx.x >> 6, lane = threadIdx.x & 63;
    int n = blockIdx.x * 4 + wid;
    int s = lane & 3, k = lane >> 2;

    int j = idx[(size_t)n * KNB + k];

    // issue the full Y gather set up front (memory-level parallelism)
    f16x2 yv[16];
    #pragma unroll
    for (int kk = 0; kk < KNB; ++kk) {
        int jk = __shfl(j, kk * 4, 64);
        yv[kk] = *(const f16x2*)(Yh + (size_t)jk * D + lane * 2);
    }
    float2 bv;
    if (use16) {
        f16x2 t = *(const f16x2*)(baseh + (size_t)n * D + lane * 2);
        bv.x = (float)t[0];
        bv.y = (float)t[1];
    } else {
        bv = *(const float2*)(out + (size_t)n * D + lane * 2);
    }

    // cosine dot on fp8-normalized rows: lane = (k, 32-elem slice s); w = dot directly
    const uint4* pj = (const uint4*)(fp8n + (size_t)j * 128 + s * 32);
    const uint4* pn = (const uint4*)(fp8n + (size_t)n * 128 + s * 32);
    uint4 xa = pj[0], xb = pj[1];
    uint4 ya = pn[0], yb = pn[1];
    float p = 0.f;
    auto dot4 = [&p](u32 xw, u32 yw) {
        f32x2 x0 = __builtin_amdgcn_cvt_pk_f32_fp8(xw, false);
        f32x2 x1 = __builtin_amdgcn_cvt_pk_f32_fp8(xw, true);
        f32x2 y0 = __builtin_amdgcn_cvt_pk_f32_fp8(yw, false);
        f32x2 y1 = __builtin_amdgcn_cvt_pk_f32_fp8(yw, true);
        p = fmaf(x0.x, y0.x, p); p = fmaf(x0.y, y0.y, p);
        p = fmaf(x1.x, y1.x, p); p = fmaf(x1.y, y1.y, p);
    };
    dot4(xa.x, ya.x); dot4(xa.y, ya.y); dot4(xa.z, ya.z); dot4(xa.w, ya.w);
    dot4(xb.x, yb.x); dot4(xb.y, yb.y); dot4(xb.z, yb.z); dot4(xb.w, yb.w);
    p += __shfl_xor(p, 1, 64);
    p += __shfl_xor(p, 2, 64);

    // combine: lane owns cols 2*lane, 2*lane+1
    float a0 = -INFINITY, a1 = -INFINITY;
    #pragma unroll
    for (int kk = 0; kk < KNB; ++kk) {
        float wk = __shfl(p, kk * 4, 64);
        a0 = fmaxf(a0, ((float)yv[kk][0] + bv.x) * wk);
        a1 = fmaxf(a1, ((float)yv[kk][1] + bv.y) * wk);
    }
    *(float2*)(out + (size_t)n * D + lane * 2) = make_float2(a0, a1);
}

extern "C" void kernel_launch(void* const* d_in, const int* in_sizes, int n_in,
                              void* d_out, int out_size, void* d_ws, size_t ws_size,
                              hipStream_t stream) {
    const float* fp  = (const float*)d_in[0];   // (N,128) f32
    const int*   idx = (const int*)d_in[1];     // (N,16) int32
    const float* W   = (const float*)d_in[2];   // (128,256) f32
    const float* b   = (const float*)d_in[3];   // (128,) f32
    float* out = (float*)d_out;                 // (N,128) f32

    char* ws = (char*)d_ws;
    unsigned char* fp8n = (unsigned char*)ws;            // 6.4 MB (fp8 e4m3 normalized rows)
    f16* Yh    = (f16*)(ws + (size_t)NROWS * 128);       // 12.8 MB
    f16* baseh = (f16*)(ws + (size_t)3 * NROWS * 128);   // 12.8 MB (only if ws large enough)

    // baseh path needs 32e6 bytes of workspace; otherwise keep base f32 in `out`
    int use16 = (ws_size >= (size_t)4 * NROWS * 128) ? 1 : 0;

    gemm_kernel<<<(NROWS + 127) / 128, 512, 0, stream>>>(fp, W, b, fp8n, Yh, baseh, out, use16);
    main_kernel<<<NROWS / 4, 256, 0, stream>>>(fp8n, idx, Yh, baseh, out, use16);
}

// Round 13
// 64.318 us; speedup vs baseline: 1.0332x; 1.0332x over previous
//
#include <hip/hip_runtime.h>
#include <hip/hip_fp16.h>
#include <math.h>

#define NROWS 50000
#define D 128
#define KNB 16

typedef _Float16 f16;
typedef _Float16 f16x8 __attribute__((ext_vector_type(8)));
typedef _Float16 f16x2 __attribute__((ext_vector_type(2)));
typedef float f32x4 __attribute__((ext_vector_type(4)));
typedef float f32x2 __attribute__((ext_vector_type(2)));
typedef unsigned int u32;

// ---- fused gemm: W->LDS(f16,swizzled,64KB); MFMA accs held in regs; after barrier #2
//      wlds is REUSED as the per-wave C-tile buffer -> coalesced 16B global stores ----
__global__ __launch_bounds__(512) void gemm_kernel(const float* __restrict__ fp,
                                                   const float* __restrict__ W,
                                                   const float* __restrict__ b,
                                                   unsigned char* __restrict__ fp8n,
                                                   f16* __restrict__ Yh,
                                                   f16* __restrict__ baseh,
                                                   float* __restrict__ basef,
                                                   int use16) {
    __shared__ f16 wlds[256 * 128];   // 64 KB: W during MFMA, then C tiles during epilogue
    int tid = threadIdx.x;
    int wid = tid >> 6, lane = tid & 63;
    int r = lane & 15, kg = lane >> 4;
    int row0 = blockIdx.x * 128 + wid * 16;
    bool valid = row0 < NROWS;

    // --- hoist fp row loads + bias loads above staging (latency overlap) ---
    f32x4 v[8];
    float bias8[8];
    if (valid) {
        const float* src = fp + (size_t)(row0 + r) * D + kg * 8;
        #pragma unroll
        for (int kc = 0; kc < 4; ++kc) {
            v[2 * kc]     = *(const f32x4*)(src + kc * 32);
            v[2 * kc + 1] = *(const f32x4*)(src + kc * 32 + 4);
        }
        #pragma unroll
        for (int q = 0; q < 8; ++q) bias8[q] = b[q * 16 + r];
    }

    // stage W (128x256 f32) -> LDS as f16 concat layout, coalesced 32B reads per thread
    #pragma unroll
    for (int it = 0; it < 8; ++it) {
        int g = tid + it * 512;          // 8-float group, 4096 total
        int i = g * 8;                   // flat index into W
        int c_w = i >> 8;                // W row (0..127)
        int kk = i & 255;                // W col (0..255)
        int destrow = (kk < 128) ? c_w : c_w + 128;
        int k = kk & 127;
        int chunk = (k >> 3) ^ (destrow & 15);
        f32x4 v0 = *(const f32x4*)(W + i);
        f32x4 v1 = *(const f32x4*)(W + i + 4);
        f16x8 h;
        #pragma unroll
        for (int e = 0; e < 4; ++e) { h[e] = (f16)v0[e]; h[4 + e] = (f16)v1[e]; }
        *(f16x8*)(wlds + destrow * 128 + chunk * 8) = h;
    }
    __syncthreads();

    // ssq -> rn; A-frags (f16) + fp8 e4m3 normalized row for the cosine table
    f16x8 a[4];
    if (valid) {
        float ssq = 0.f;
        #pragma unroll
        for (int q = 0; q < 8; ++q) {
            #pragma unroll
            for (int e = 0; e < 4; ++e) ssq = fmaf(v[q][e], v[q][e], ssq);
        }
        ssq += __shfl_xor(ssq, 16, 64);
        ssq += __shfl_xor(ssq, 32, 64);  // all lanes: full row ssq
        float rn = rsqrtf(ssq);

        #pragma unroll
        for (int kc = 0; kc < 4; ++kc) {
            f16x8 h;
            float nx[8];
            #pragma unroll
            for (int e = 0; e < 4; ++e) {
                float x0 = v[2 * kc][e], x1 = v[2 * kc + 1][e];
                h[e] = (f16)x0;        h[4 + e] = (f16)x1;
                nx[e] = x0 * rn;       nx[4 + e] = x1 * rn;
            }
            a[kc] = h;
            u32 lo = __builtin_amdgcn_cvt_pk_fp8_f32(nx[0], nx[1], 0u, false);
            lo     = __builtin_amdgcn_cvt_pk_fp8_f32(nx[2], nx[3], lo, true);
            u32 hi = __builtin_amdgcn_cvt_pk_fp8_f32(nx[4], nx[5], 0u, false);
            hi     = __builtin_amdgcn_cvt_pk_fp8_f32(nx[6], nx[7], hi, true);
            uint2 st; st.x = lo; st.y = hi;
            *(uint2*)(fp8n + (size_t)(row0 + r) * 128 + kc * 32 + kg * 8) = st;
        }
    }

    // MFMA: all 16 col-tiles, accumulators held in registers (~64 VGPR)
    f32x4 acc[16];
    if (valid) {
        #pragma unroll
        for (int ct = 0; ct < 16; ++ct) {
            f32x4 t = {0.f, 0.f, 0.f, 0.f};
            #pragma unroll
            for (int kc = 0; kc < 4; ++kc) {
                int sc = (kc * 4 + kg) ^ r;  // swizzled chunk (matches staging XOR)
                f16x8 bf = *(const f16x8*)(wlds + (ct * 16 + r) * 128 + sc * 8);
                t = __builtin_amdgcn_mfma_f32_16x16x32_f16(a[kc], bf, t, 0, 0, 0);
            }
            acc[ct] = t;
        }
    }
    __syncthreads();   // all W reads retired; wlds is now free for C tiles

    if (valid) {
        // write C (bias folded) into this wave's 8 KB slice, chunk-XOR swizzled
        f16* cw = wlds + wid * 4096;     // 16 rows x 256 cols f16
        #pragma unroll
        for (int ct = 0; ct < 16; ++ct) {
            int col = ct * 16 + r;
            float add = (ct >= 8) ? bias8[ct - 8] : 0.0f;
            #pragma unroll
            for (int i = 0; i < 4; ++i) {
                int row = kg * 4 + i;    // 0..15
                cw[row * 256 + (((col >> 3) ^ kg) << 3) + (col & 7)] = (f16)(acc[ct][i] + add);
            }
        }
        // coalesced flush: each lane 8 chunks of 16B from its wave's own region
        #pragma unroll
        for (int it = 0; it < 8; ++it) {
            int c = lane + it * 64;      // chunk id 0..511
            int row = c >> 5;            // 0..15
            int cc = c & 31;             // logical 8-f16 chunk within row
            f16x8 val = *(const f16x8*)(cw + row * 256 + ((cc ^ (row >> 2)) << 3));
            int col0 = cc * 8;           // 0..248
            size_t grow = (size_t)(row0 + row) * 128;
            if (col0 < 128) {
                *(f16x8*)(Yh + grow + col0) = val;
            } else if (use16) {
                *(f16x8*)(baseh + grow + (col0 - 128)) = val;
            } else {
                f32x4 lo, hi;
                #pragma unroll
                for (int e = 0; e < 4; ++e) { lo[e] = (float)val[e]; hi[e] = (float)val[4 + e]; }
                *(f32x4*)(basef + grow + (col0 - 128)) = lo;
                *(f32x4*)(basef + grow + (col0 - 124)) = hi;
            }
        }
    }
}

// ---- main: one wave per n; all 16 Y-gathers issued first; fp8 cosine dots ----
__global__ __launch_bounds__(256) void main_kernel(const unsigned char* __restrict__ fp8n,
                                                   const int* __restrict__ idx,
                                                   const f16* __restrict__ Yh,
                                                   const f16* __restrict__ baseh,
                                                   float* __restrict__ out,
                                                   int use16) {
    int wid = threadIdx.x >> 6, lane = threadIdx.x & 63;
    int n = blockIdx.x * 4 + wid;
    int s = lane & 3, k = lane >> 2;

    int j = idx[(size_t)n * KNB + k];

    // issue the full Y gather set up front (memory-level parallelism)
    f16x2 yv[16];
    #pragma unroll
    for (int kk = 0; kk < KNB; ++kk) {
        int jk = __shfl(j, kk * 4, 64);
        yv[kk] = *(const f16x2*)(Yh + (size_t)jk * D + lane * 2);
    }
    float2 bv;
    if (use16) {
        f16x2 t = *(const f16x2*)(baseh + (size_t)n * D + lane * 2);
        bv.x = (float)t[0];
        bv.y = (float)t[1];
    } else {
        bv = *(const float2*)(out + (size_t)n * D + lane * 2);
    }

    // cosine dot on fp8-normalized rows: lane = (k, 32-elem slice s); w = dot directly
    const uint4* pj = (const uint4*)(fp8n + (size_t)j * 128 + s * 32);
    const uint4* pn = (const uint4*)(fp8n + (size_t)n * 128 + s * 32);
    uint4 xa = pj[0], xb = pj[1];
    uint4 ya = pn[0], yb = pn[1];
    float p = 0.f;
    auto dot4 = [&p](u32 xw, u32 yw) {
        f32x2 x0 = __builtin_amdgcn_cvt_pk_f32_fp8(xw, false);
        f32x2 x1 = __builtin_amdgcn_cvt_pk_f32_fp8(xw, true);
        f32x2 y0 = __builtin_amdgcn_cvt_pk_f32_fp8(yw, false);
        f32x2 y1 = __builtin_amdgcn_cvt_pk_f32_fp8(yw, true);
        p = fmaf(x0.x, y0.x, p); p = fmaf(x0.y, y0.y, p);
        p = fmaf(x1.x, y1.x, p); p = fmaf(x1.y, y1.y, p);
    };
    dot4(xa.x, ya.x); dot4(xa.y, ya.y); dot4(xa.z, ya.z); dot4(xa.w, ya.w);
    dot4(xb.x, yb.x); dot4(xb.y, yb.y); dot4(xb.z, yb.z); dot4(xb.w, yb.w);
    p += __shfl_xor(p, 1, 64);
    p += __shfl_xor(p, 2, 64);

    // combine: lane owns cols 2*lane, 2*lane+1
    float a0 = -INFINITY, a1 = -INFINITY;
    #pragma unroll
    for (int kk = 0; kk < KNB; ++kk) {
        float wk = __shfl(p, kk * 4, 64);
        a0 = fmaxf(a0, ((float)yv[kk][0] + bv.x) * wk);
        a1 = fmaxf(a1, ((float)yv[kk][1] + bv.y) * wk);
    }
    *(float2*)(out + (size_t)n * D + lane * 2) = make_float2(a0, a1);
}

extern "C" void kernel_launch(void* const* d_in, const int* in_sizes, int n_in,
                              void* d_out, int out_size, void* d_ws, size_t ws_size,
                              hipStream_t stream) {
    const float* fp  = (const float*)d_in[0];   // (N,128) f32
    const int*   idx = (const int*)d_in[1];     // (N,16) int32
    const float* W   = (const float*)d_in[2];   // (128,256) f32
    const float* b   = (const float*)d_in[3];   // (128,) f32
    float* out = (float*)d_out;                 // (N,128) f32

    char* ws = (char*)d_ws;
    unsigned char* fp8n = (unsigned char*)ws;            // 6.4 MB (fp8 e4m3 normalized rows)
    f16* Yh    = (f16*)(ws + (size_t)NROWS * 128);       // 12.8 MB
    f16* baseh = (f16*)(ws + (size_t)3 * NROWS * 128);   // 12.8 MB (only if ws large enough)

    // baseh path needs 32e6 bytes of workspace; otherwise keep base f32 in `out`
    int use16 = (ws_size >= (size_t)4 * NROWS * 128) ? 1 : 0;

    gemm_kernel<<<(NROWS + 127) / 128, 512, 0, stream>>>(fp, W, b, fp8n, Yh, baseh, out, use16);
    main_kernel<<<NROWS / 4, 256, 0, stream>>>(fp8n, idx, Yh, baseh, out, use16);
}